// Round 11
// baseline (386.653 us; speedup 1.0000x reference)
//
#include <hip/hip_runtime.h>
#include <hip/hip_bf16.h>
#include <float.h>

// ---------------------------------------------------------------------------
// ImprovedTransformerGNN: bf16-MFMA GEMMs, bf16-resident h, fp32 accum.
// N=50000, E=600000, H=128, IN=128, C=4, L=3, G=128.
// R11: structural fusions, numerics IDENTICAL to R10:
//   (1) proj1+proj2 fused (h1 via 16KB swizzled LDS, not 25.6MB global trip);
//   (2) GCN layer-3 GEMM + aw-GEMM fused (h via LDS);
//   (3) scan_bsum folded into scan_add.  22 -> 19 dispatches.
// ---------------------------------------------------------------------------

#define GGRAPHS 128
#define POOL_NC 16

typedef __attribute__((ext_vector_type(8))) short short8b;  // 8 bf16 = 4 VGPR
typedef __attribute__((ext_vector_type(4))) float f32x4;

__device__ __forceinline__ float gelu_f(float x) {
    return 0.5f * x * (1.0f + erff(x * 0.7071067811865476f));
}

__device__ __forceinline__ unsigned short f2bf(float f) {  // RNE, finite inputs
    unsigned int u = __float_as_uint(f);
    unsigned int r = (u + 0x7FFFu + ((u >> 16) & 1u)) >> 16;
    return (unsigned short)r;
}

__device__ __forceinline__ float bf2f(unsigned short u) {
    return __uint_as_float(((unsigned int)u) << 16);
}

static constexpr float BNS_F = 0.99999500003749968f;  // 1/sqrt(1+1e-5)

// ---------------------------------------------------------------------------
// one-shot weight prep: 5x [128][128] + 1x [128][64] fp32 W -> bf16 W^T [M][K]
// ---------------------------------------------------------------------------
__global__ void transpose_all_kernel(const float* __restrict__ W1, const float* __restrict__ W2,
                                     const float* __restrict__ Wg, const float* __restrict__ Wa1,
                                     unsigned short* __restrict__ Wt1, unsigned short* __restrict__ Wt2,
                                     unsigned short* __restrict__ Wtg, unsigned short* __restrict__ Wta1)
{
    const int id = blockIdx.x * 256 + threadIdx.x;
    if (id < 81920) {
        const int m = id >> 14;           // 0:W1 1:W2 2..4:Wg[l]
        const int r = id & 16383;
        const int k = r >> 7, c = r & 127;
        const float* Wsrc = (m == 0) ? W1 : (m == 1) ? W2 : Wg + (size_t)(m - 2) * 16384;
        unsigned short* Wdst = (m == 0) ? Wt1 : (m == 1) ? Wt2 : Wtg + (size_t)(m - 2) * 16384;
        Wdst[c * 128 + k] = f2bf(Wsrc[r]);
    } else if (id < 90112) {
        const int r = id - 81920;         // Wa1 [128][64]
        const int k = r >> 6, c = r & 63;
        Wta1[c * 128 + k] = f2bf(Wa1[r]);
    }
}

// ---------------------------------------------------------------------------
// LDS staging helper (device inline): stage W^T [M][128] bf16 XOR-swizzled.
// byte ^= ((byte>>8)&7)<<4  (row = byte>>8, 256B rows).
// ---------------------------------------------------------------------------
template<int M>
__device__ __forceinline__ void stage_wt(const unsigned short* __restrict__ Wtb,
                                         unsigned short* __restrict__ Wl, int tid)
{
#pragma unroll
    for (int i = 0; i < (M * 16) / 256; ++i) {
        const int idx = i * 256 + tid;
        const uint4 v = reinterpret_cast<const uint4*>(Wtb)[idx];
        const int byte = idx * 16;
        const int swz = byte ^ (((byte >> 8) & 7) << 4);
        *reinterpret_cast<uint4*>(reinterpret_cast<char*>(Wl) + swz) = v;
    }
}

// MFMA stage over LDS W^T: acc[ct] += A @ W; A-frags given.
template<int NCT>
__device__ __forceinline__ void mfma_stage(const short8b* a, const unsigned short* __restrict__ Wl,
                                           f32x4* acc, int l4, int lm)
{
    const int swzm = (lm & 7) << 4;
    const char* Wlc = reinterpret_cast<const char*>(Wl);
#pragma unroll
    for (int ks = 0; ks < 4; ++ks) {
#pragma unroll
        for (int ct = 0; ct < NCT; ++ct) {
            const int byte = ct * 4096 + lm * 256 + ks * 64 + l4 * 16;
            const short8b bv = *reinterpret_cast<const short8b*>(Wlc + (byte ^ swzm));
            acc[ct] = __builtin_amdgcn_mfma_f32_16x16x32_bf16(a[ks], bv, acc[ct], 0, 0, 0);
        }
    }
}

// load A-frags (4 k-steps) from bf16 global row
__device__ __forceinline__ void load_afrag_bf(const unsigned short* __restrict__ ap, short8b* a)
{
#pragma unroll
    for (int ks = 0; ks < 4; ++ks)
        a[ks] = *reinterpret_cast<const short8b*>(ap + ks * 32);
}

// load A-frags from swizzled LDS h tile (row = local row, 256B rows)
__device__ __forceinline__ void load_afrag_lds(const unsigned short* __restrict__ hl,
                                               int rowl, int l4, short8b* a)
{
    const char* hc = reinterpret_cast<const char*>(hl);
    const int swz = (rowl & 7) << 4;
#pragma unroll
    for (int ks = 0; ks < 4; ++ks) {
        const int byte = rowl * 256 + ks * 64 + l4 * 16;
        a[ks] = *reinterpret_cast<const short8b*>(hc + (byte ^ swz));
    }
}

// store one bf16 value into swizzled LDS h tile
__device__ __forceinline__ void store_h_lds(unsigned short* __restrict__ hl,
                                            int rowl, int col, unsigned short v)
{
    const int byte = (rowl * 256 + col * 2) ^ ((rowl & 7) << 4);
    *reinterpret_cast<unsigned short*>(reinterpret_cast<char*>(hl) + byte) = v;
}

// ---------------------------------------------------------------------------
// Fused input projection: hbf = bf16(gelu(bn( gelu(bn(x@W1)) @ W2 )))
// x fp32 (converted in-reg). h1 via 16KB swizzled LDS. LDS total 80KB.
// ---------------------------------------------------------------------------
__global__ __launch_bounds__(256, 2)
void proj_fused(const float* __restrict__ x,
                const unsigned short* __restrict__ Wt1, const unsigned short* __restrict__ Wt2,
                const float* __restrict__ b1, const float* __restrict__ g1, const float* __restrict__ be1,
                const float* __restrict__ b2, const float* __restrict__ g2, const float* __restrict__ be2,
                unsigned short* __restrict__ hbf, int nrows)
{
    __shared__ unsigned short W1l[128 * 128];  // 32KB
    __shared__ unsigned short W2l[128 * 128];  // 32KB
    __shared__ unsigned short h1l[64 * 128];   // 16KB

    const int tid = threadIdx.x;
    stage_wt<128>(Wt1, W1l, tid);
    stage_wt<128>(Wt2, W2l, tid);
    __syncthreads();

    const int w = tid >> 6;
    const int l = tid & 63;
    const int l4 = l >> 4, lm = l & 15;
    const int rowbase = (int)blockIdx.x * 64 + w * 16;

    // ---- stage 1: x @ W1 ----
    int arow = rowbase + lm; if (arow >= nrows) arow = nrows - 1;
    const float* apf = x + (size_t)arow * 128 + l4 * 8;
    short8b a[4];
#pragma unroll
    for (int ks = 0; ks < 4; ++ks) {
        const float4 v0 = *reinterpret_cast<const float4*>(apf + ks * 32);
        const float4 v1 = *reinterpret_cast<const float4*>(apf + ks * 32 + 4);
        short8b av;
        av[0] = (short)f2bf(v0.x); av[1] = (short)f2bf(v0.y);
        av[2] = (short)f2bf(v0.z); av[3] = (short)f2bf(v0.w);
        av[4] = (short)f2bf(v1.x); av[5] = (short)f2bf(v1.y);
        av[6] = (short)f2bf(v1.z); av[7] = (short)f2bf(v1.w);
        a[ks] = av;
    }

    f32x4 acc[8];
#pragma unroll
    for (int ct = 0; ct < 8; ++ct) acc[ct] = f32x4{0.f, 0.f, 0.f, 0.f};
    mfma_stage<8>(a, W1l, acc, l4, lm);

    // epilogue 1 -> h1l (bf16, swizzled)
#pragma unroll
    for (int ct = 0; ct < 8; ++ct) {
        const int col = ct * 16 + lm;
        const float g = g1[col];
        const float sc = g * BNS_F;
        const float bi = b1[col] * sc + be1[col];
#pragma unroll
        for (int rid = 0; rid < 4; ++rid) {
            const int rowl = w * 16 + l4 * 4 + rid;
            float v = acc[ct][rid] * sc + bi;
            v = gelu_f(v);
            store_h_lds(h1l, rowl, col, f2bf(v));
        }
    }
    __syncthreads();

    // ---- stage 2: h1 @ W2 ----
    load_afrag_lds(h1l, w * 16 + lm, l4, a);
#pragma unroll
    for (int ct = 0; ct < 8; ++ct) acc[ct] = f32x4{0.f, 0.f, 0.f, 0.f};
    mfma_stage<8>(a, W2l, acc, l4, lm);

#pragma unroll
    for (int ct = 0; ct < 8; ++ct) {
        const int col = ct * 16 + lm;
        const float g = g2[col];
        const float sc = g * BNS_F;
        const float bi = b2[col] * sc + be2[col];
#pragma unroll
        for (int rid = 0; rid < 4; ++rid) {
            const int row = rowbase + l4 * 4 + rid;
            if (row < nrows) {
                float v = acc[ct][rid] * sc + bi;
                v = gelu_f(v);
                hbf[(size_t)row * 128 + col] = f2bf(v);
            }
        }
    }
}

// ---------------------------------------------------------------------------
// Generic MFMA GEMM (GCN layers 1,2): hbf = bf16(gelu(bn(A@W)) + hbf_resid)
// ---------------------------------------------------------------------------
__global__ __launch_bounds__(256, 2)
void gemm_gcn(const unsigned short* __restrict__ Abf,
              const unsigned short* __restrict__ Wtb,
              const float* __restrict__ bias, const float* __restrict__ gam,
              const float* __restrict__ beta, unsigned short* __restrict__ hbf,
              int nrows)
{
    __shared__ unsigned short Wl[128 * 128];   // 32KB

    const int tid = threadIdx.x;
    stage_wt<128>(Wtb, Wl, tid);
    __syncthreads();

    const int w = tid >> 6;
    const int l = tid & 63;
    const int l4 = l >> 4, lm = l & 15;
    const int rowbase = (int)blockIdx.x * 64 + w * 16;

    int arow = rowbase + lm; if (arow >= nrows) arow = nrows - 1;
    short8b a[4];
    load_afrag_bf(Abf + (size_t)arow * 128 + l4 * 8, a);

    f32x4 acc[8];
#pragma unroll
    for (int ct = 0; ct < 8; ++ct) acc[ct] = f32x4{0.f, 0.f, 0.f, 0.f};
    mfma_stage<8>(a, Wl, acc, l4, lm);

#pragma unroll
    for (int ct = 0; ct < 8; ++ct) {
        const int col = ct * 16 + lm;
        const float g = gam[col];
        const float sc = g * BNS_F;
        const float bi = bias[col] * sc + beta[col];
#pragma unroll
        for (int rid = 0; rid < 4; ++rid) {
            const int row = rowbase + l4 * 4 + rid;
            if (row < nrows) {
                float v = acc[ct][rid] * sc + bi;
                v = gelu_f(v);
                v += bf2f(hbf[(size_t)row * 128 + col]);
                hbf[(size_t)row * 128 + col] = f2bf(v);
            }
        }
    }
}

// ---------------------------------------------------------------------------
// Fused GCN layer 3 + attention weights:
//   h = bf16(gelu(bn(A@W3)) + resid) -> hbf AND LDS;
//   aw = tanh( gelu(h@Wa1+ba1) @ Wa2 + ba2 ).  LDS: 32+16+16 = 64KB.
// ---------------------------------------------------------------------------
__global__ __launch_bounds__(256, 2)
void gcn_aw_fused(const unsigned short* __restrict__ Abf,
                  const unsigned short* __restrict__ Wt3,
                  const float* __restrict__ bias, const float* __restrict__ gam,
                  const float* __restrict__ beta, unsigned short* __restrict__ hbf,
                  const unsigned short* __restrict__ Wta1, const float* __restrict__ ba1,
                  const float* __restrict__ Wa2, const float* __restrict__ ba2,
                  float* __restrict__ awout, int nrows)
{
    __shared__ unsigned short W3l[128 * 128];  // 32KB
    __shared__ unsigned short Wa1l[64 * 128];  // 16KB
    __shared__ unsigned short hl[64 * 128];    // 16KB

    const int tid = threadIdx.x;
    stage_wt<128>(Wt3, W3l, tid);
    stage_wt<64>(Wta1, Wa1l, tid);
    __syncthreads();

    const int w = tid >> 6;
    const int l = tid & 63;
    const int l4 = l >> 4, lm = l & 15;
    const int rowbase = (int)blockIdx.x * 64 + w * 16;

    int arow = rowbase + lm; if (arow >= nrows) arow = nrows - 1;
    short8b a[4];
    load_afrag_bf(Abf + (size_t)arow * 128 + l4 * 8, a);

    f32x4 acc[8];
#pragma unroll
    for (int ct = 0; ct < 8; ++ct) acc[ct] = f32x4{0.f, 0.f, 0.f, 0.f};
    mfma_stage<8>(a, W3l, acc, l4, lm);

    // epilogue: h -> hbf (global) + hl (LDS swizzled)
#pragma unroll
    for (int ct = 0; ct < 8; ++ct) {
        const int col = ct * 16 + lm;
        const float g = gam[col];
        const float sc = g * BNS_F;
        const float bi = bias[col] * sc + beta[col];
#pragma unroll
        for (int rid = 0; rid < 4; ++rid) {
            const int row = rowbase + l4 * 4 + rid;
            const int rowl = w * 16 + l4 * 4 + rid;
            float v = acc[ct][rid] * sc + bi;
            v = gelu_f(v);
            unsigned short hv;
            if (row < nrows) {
                v += bf2f(hbf[(size_t)row * 128 + col]);
                hv = f2bf(v);
                hbf[(size_t)row * 128 + col] = hv;
            } else {
                hv = 0;
            }
            store_h_lds(hl, rowl, col, hv);
        }
    }
    __syncthreads();

    // ---- aw stage: t = h @ Wa1 (M=64), aw = tanh(gelu(t) . Wa2 + ba2) ----
    load_afrag_lds(hl, w * 16 + lm, l4, a);
    f32x4 acc2[4];
#pragma unroll
    for (int ct = 0; ct < 4; ++ct) acc2[ct] = f32x4{0.f, 0.f, 0.f, 0.f};
    mfma_stage<4>(a, Wa1l, acc2, l4, lm);

    float p[4] = {0.f, 0.f, 0.f, 0.f};
#pragma unroll
    for (int ct = 0; ct < 4; ++ct) {
        const int col = ct * 16 + lm;
        const float bi = ba1[col];
        const float wa = Wa2[col];
#pragma unroll
        for (int rid = 0; rid < 4; ++rid) {
            float v = acc2[ct][rid] + bi;
            v = gelu_f(v);
            p[rid] = fmaf(v, wa, p[rid]);
        }
    }
    const float ba2v = ba2[0];
#pragma unroll
    for (int rid = 0; rid < 4; ++rid) {
        float v = p[rid];
        v += __shfl_xor(v, 1);
        v += __shfl_xor(v, 2);
        v += __shfl_xor(v, 4);
        v += __shfl_xor(v, 8);
        const int row = rowbase + l4 * 4 + rid;
        if (lm == 0 && row < nrows) awout[row] = tanhf(v + ba2v);
    }
}

// ---------------------------------------------------------------------------
// CSR build: count + per-edge rank (atomic), scan (+dinv), atomic-free fill.
// ---------------------------------------------------------------------------
__global__ void count_rank_kernel(const int* __restrict__ dst, int* __restrict__ cnt,
                                  int* __restrict__ rank, int E)
{
    int e = blockIdx.x * 256 + threadIdx.x;
    if (e < E) rank[e] = atomicAdd(&cnt[dst[e]], 1);
}

__global__ void scan_local(const int* __restrict__ cnt, int* __restrict__ rowptr,
                           int* __restrict__ bsum, float* __restrict__ dinv, int n)
{
    __shared__ int sd[1024];
    const int tid = threadIdx.x;
    const int i = blockIdx.x * 1024 + tid;
    int v = (i < n) ? cnt[i] : 0;
    if (i < n) dinv[i] = rsqrtf((float)v + 1.0f);
    sd[tid] = v;
    __syncthreads();
    for (int off = 1; off < 1024; off <<= 1) {
        int t = (tid >= off) ? sd[tid - off] : 0;
        __syncthreads();
        sd[tid] += t;
        __syncthreads();
    }
    if (i < n) rowptr[i + 1] = sd[tid];
    if (tid == 1023) bsum[blockIdx.x] = sd[1023];
}

// scan_add with inline bsum-prefix (nb <= 64)
__global__ void scan_add(int* __restrict__ rowptr, const int* __restrict__ bsum, int n)
{
    __shared__ int pref;
    const int bid = blockIdx.x;
    if (threadIdx.x < 64) {
        int v = ((int)threadIdx.x < bid) ? bsum[threadIdx.x] : 0;
#pragma unroll
        for (int off = 32; off; off >>= 1) v += __shfl_xor(v, off);
        if (threadIdx.x == 0) pref = v;
    }
    __syncthreads();
    const int i = bid * 1024 + threadIdx.x;
    if (i < n) rowptr[i + 1] += pref;
    if (i == 0) rowptr[0] = 0;
}

__global__ void fill_kernel(const int* __restrict__ src, const int* __restrict__ dst,
                            const float* __restrict__ dinv, const int* __restrict__ rowptr,
                            const int* __restrict__ rank, int2* __restrict__ csr, int E)
{
    int e = blockIdx.x * 256 + threadIdx.x;
    if (e < E) {
        const int d = dst[e], s = src[e];
        const int pos = rowptr[d] + rank[e];
        int2 p;
        p.x = s;
        p.y = __float_as_int(dinv[s] * dinv[d]);
        csr[pos] = p;
    }
}

// ---------------------------------------------------------------------------
// Aggregation (gather over CSR, bf16 rows): ah = h*snorm + sum h[src]*w
// ---------------------------------------------------------------------------
#define FMAB(A, Wt, U) { A.x = fmaf(Wt, bf2f(U.x), A.x); A.y = fmaf(Wt, bf2f(U.y), A.y); \
                         A.z = fmaf(Wt, bf2f(U.z), A.z); A.w = fmaf(Wt, bf2f(U.w), A.w); }

__global__ __launch_bounds__(256)
void agg_kernel(const ushort4* __restrict__ hb, const int2* __restrict__ csr,
                const int* __restrict__ rowptr, const float* __restrict__ dinv,
                ushort4* __restrict__ ahb, int n)
{
    const int node = blockIdx.x * 8 + (threadIdx.x >> 5);
    if (node >= n) return;
    const int lane = threadIdx.x & 31;

    const float di = dinv[node];
    const float sw = di * di;
    const ushort4 sv = hb[(size_t)node * 32 + lane];
    float4 a0, a1;
    a0.x = bf2f(sv.x) * sw; a0.y = bf2f(sv.y) * sw;
    a0.z = bf2f(sv.z) * sw; a0.w = bf2f(sv.w) * sw;
    a1.x = 0.f; a1.y = 0.f; a1.z = 0.f; a1.w = 0.f;

    const int beg = rowptr[node], end = rowptr[node + 1];
    int s = beg;
    for (; s + 4 <= end; s += 4) {
        const int2 e0 = csr[s+0], e1 = csr[s+1], e2 = csr[s+2], e3 = csr[s+3];
        const ushort4 v0 = hb[(size_t)e0.x * 32 + lane];
        const ushort4 v1 = hb[(size_t)e1.x * 32 + lane];
        const ushort4 v2 = hb[(size_t)e2.x * 32 + lane];
        const ushort4 v3 = hb[(size_t)e3.x * 32 + lane];
        FMAB(a0, __int_as_float(e0.y), v0); FMAB(a1, __int_as_float(e1.y), v1);
        FMAB(a0, __int_as_float(e2.y), v2); FMAB(a1, __int_as_float(e3.y), v3);
    }
    for (; s < end; ++s) {
        const int2 e0 = csr[s];
        const ushort4 v = hb[(size_t)e0.x * 32 + lane];
        FMAB(a0, __int_as_float(e0.y), v);
    }
    ushort4 q;
    q.x = f2bf(a0.x + a1.x); q.y = f2bf(a0.y + a1.y);
    q.z = f2bf(a0.z + a1.z); q.w = f2bf(a0.w + a1.w);
    ahb[(size_t)node * 32 + lane] = q;
}

// ---------------------------------------------------------------------------
// pooling over sorted batch; graph bounds via inline binary search.
// ---------------------------------------------------------------------------
__device__ __forceinline__ int lb_batch(const int* __restrict__ batch, int n, int t)
{
    int lo = 0, hi = n;
    while (lo < hi) { int mid = (lo + hi) >> 1; if (batch[mid] < t) lo = mid + 1; else hi = mid; }
    return lo;
}

__global__ void pool_partial(const unsigned short* __restrict__ h, const float* __restrict__ aw,
                             const int* __restrict__ batch, int n, float* __restrict__ ps,
                             float* __restrict__ pm, float* __restrict__ pw)
{
    const int g = blockIdx.x >> 4;
    const int c = blockIdx.x & (POOL_NC - 1);
    const int f = threadIdx.x;  // 128 threads
    const int beg = lb_batch(batch, n, g), end = lb_batch(batch, n, g + 1);
    const int len = end - beg;
    const int cbeg = beg + (int)(((long long)len * c) / POOL_NC);
    const int cend = beg + (int)(((long long)len * (c + 1)) / POOL_NC);
    float s = 0.f, m = -FLT_MAX, w = 0.f;
    for (int node = cbeg; node < cend; ++node) {
        const float v = bf2f(h[(size_t)node * 128 + f]);
        const float a = aw[node];
        s += v;
        m = fmaxf(m, v);
        w = fmaf(v, a, w);
    }
    const size_t idx = ((size_t)g * POOL_NC + c) * 128 + f;
    ps[idx] = s; pm[idx] = m; pw[idx] = w;
}

__global__ void pool_final(const float* __restrict__ ps, const float* __restrict__ pm,
                           const float* __restrict__ pw, const int* __restrict__ batch,
                           int n, float* __restrict__ comb)
{
    const int g = blockIdx.x;
    const int f = threadIdx.x;  // 128 threads
    float s = 0.f, m = -FLT_MAX, w = 0.f;
#pragma unroll
    for (int c = 0; c < POOL_NC; ++c) {
        const size_t idx = ((size_t)g * POOL_NC + c) * 128 + f;
        s += ps[idx];
        m = fmaxf(m, pm[idx]);
        w += pw[idx];
    }
    float cn = (float)(lb_batch(batch, n, g + 1) - lb_batch(batch, n, g));
    if (cn < 1.f) cn = 1.f;
    comb[(size_t)g * 512 + f]       = s / cn;
    comb[(size_t)g * 512 + 128 + f] = m;
    comb[(size_t)g * 512 + 256 + f] = s / cn;
    comb[(size_t)g * 512 + 384 + f] = w / cn;
}

// ---------------------------------------------------------------------------
// classifier head GEMM: grid = G * (M/64); block 256 = 64 cols x 4 k-quarters.
// ---------------------------------------------------------------------------
template<int K, int M, bool DO_BN, bool DO_GELU>
__global__ __launch_bounds__(256)
void rowgemm2(const float* __restrict__ X, const float* __restrict__ W,
              const float* __restrict__ bias, const float* __restrict__ gam,
              const float* __restrict__ beta, float* __restrict__ Y)
{
    constexpr int NC = M / 64;
    constexpr int KQ = K / 4;
    const int row = blockIdx.x / NC;
    const int lane = threadIdx.x & 63;
    const int c = (blockIdx.x % NC) * 64 + lane;
    const int q = threadIdx.x >> 6;  // k-quarter 0..3

    const float* __restrict__ xq = X + (size_t)row * K + q * KQ;
    const float* __restrict__ wq = W + (size_t)(q * KQ) * M + c;

    float a0 = 0.f, a1 = 0.f, a2 = 0.f, a3 = 0.f;
#pragma unroll 4
    for (int k = 0; k < KQ; k += 4) {
        const float4 xv = *reinterpret_cast<const float4*>(xq + k);
        a0 = fmaf(xv.x, wq[(size_t)(k + 0) * M], a0);
        a1 = fmaf(xv.y, wq[(size_t)(k + 1) * M], a1);
        a2 = fmaf(xv.z, wq[(size_t)(k + 2) * M], a2);
        a3 = fmaf(xv.w, wq[(size_t)(k + 3) * M], a3);
    }
    __shared__ float part[4][64];
    part[q][lane] = (a0 + a1) + (a2 + a3);
    __syncthreads();
    if (q == 0) {
        float v = (part[0][lane] + part[1][lane]) + (part[2][lane] + part[3][lane]);
        if (DO_BN) { const float g = gam[c]; const float sc = g * BNS_F; v = v * sc + (bias[c] * sc + beta[c]); }
        else       { v = v + bias[c]; }
        if (DO_GELU) v = gelu_f(v);
        Y[(size_t)row * M + c] = v;
    }
}

// final layer: [G,64] @ [64,4] + bias; one wave per row, shuffle reduce
__global__ void rowgemm_final(const float* __restrict__ X, const float* __restrict__ W,
                              const float* __restrict__ bias, float* __restrict__ Y)
{
    const int row = blockIdx.x;
    const int lane = threadIdx.x;  // 64
    const float xv = X[(size_t)row * 64 + lane];
    const float4 wr = *reinterpret_cast<const float4*>(W + lane * 4);
    float a0 = xv * wr.x, a1 = xv * wr.y, a2 = xv * wr.z, a3 = xv * wr.w;
#pragma unroll
    for (int off = 32; off; off >>= 1) {
        a0 += __shfl_xor(a0, off);
        a1 += __shfl_xor(a1, off);
        a2 += __shfl_xor(a2, off);
        a3 += __shfl_xor(a3, off);
    }
    if (lane == 0) {
        Y[(size_t)row * 4 + 0] = a0 + bias[0];
        Y[(size_t)row * 4 + 1] = a1 + bias[1];
        Y[(size_t)row * 4 + 2] = a2 + bias[2];
        Y[(size_t)row * 4 + 3] = a3 + bias[3];
    }
}

// ---------------------------------------------------------------------------
extern "C" void kernel_launch(void* const* d_in, const int* in_sizes, int n_in,
                              void* d_out, int out_size, void* d_ws, size_t ws_size,
                              hipStream_t stream)
{
    const float* x     = (const float*)d_in[0];
    const int*   ei    = (const int*)d_in[1];
    const int*   batch = (const int*)d_in[2];
    const float* W1  = (const float*)d_in[3];
    const float* b1  = (const float*)d_in[4];
    const float* g1  = (const float*)d_in[5];
    const float* be1 = (const float*)d_in[6];
    const float* W2  = (const float*)d_in[7];
    const float* b2  = (const float*)d_in[8];
    const float* g2  = (const float*)d_in[9];
    const float* be2 = (const float*)d_in[10];
    const float* Wg  = (const float*)d_in[11];
    const float* bg  = (const float*)d_in[12];
    const float* gg  = (const float*)d_in[13];
    const float* bgg = (const float*)d_in[14];
    const float* Wa1 = (const float*)d_in[15];
    const float* ba1 = (const float*)d_in[16];
    const float* Wa2 = (const float*)d_in[17];
    const float* ba2 = (const float*)d_in[18];
    const float* Wc1 = (const float*)d_in[19];
    const float* bc1 = (const float*)d_in[20];
    const float* gc1 = (const float*)d_in[21];
    const float* bec1= (const float*)d_in[22];
    const float* Wc2 = (const float*)d_in[23];
    const float* bc2 = (const float*)d_in[24];
    const float* gc2 = (const float*)d_in[25];
    const float* bec2= (const float*)d_in[26];
    const float* Wc3 = (const float*)d_in[27];
    const float* bc3 = (const float*)d_in[28];
    const float* gc3 = (const float*)d_in[29];
    const float* bec3= (const float*)d_in[30];
    const float* Wc4 = (const float*)d_in[31];
    const float* bc4 = (const float*)d_in[32];
    float* out = (float*)d_out;

    const int N = in_sizes[0] / 128;
    const int E = in_sizes[1] / 2;
    const int G = GGRAPHS;

    // workspace carve-up
    size_t off = 0;
    auto alloc = [&](size_t bytes) -> void* {
        void* p = (char*)d_ws + off;
        off += (bytes + 255) & ~(size_t)255;
        return p;
    };
    unsigned short* hbf   = (unsigned short*)alloc((size_t)N * 128 * 2);  // bf16 h (resident)
    unsigned short* ahb   = (unsigned short*)alloc((size_t)N * 128 * 2);  // bf16 agg out
    unsigned short* Wt1   = (unsigned short*)alloc(128 * 128 * 2);
    unsigned short* Wt2   = (unsigned short*)alloc(128 * 128 * 2);
    unsigned short* Wtg   = (unsigned short*)alloc(3 * 128 * 128 * 2);
    unsigned short* Wta1  = (unsigned short*)alloc(64 * 128 * 2);
    float*   aw     = (float*)alloc((size_t)N * 4);
    float*   dinv   = (float*)alloc((size_t)N * 4);
    int*     cnt    = (int*)alloc((size_t)N * 4);
    int*     rank   = (int*)alloc((size_t)E * 4);
    int*     rowptr = (int*)alloc((size_t)(N + 1) * 4);
    int*     bsum   = (int*)alloc(64 * 4);
    int2*    csr    = (int2*)alloc((size_t)E * 8);
    float*   comb   = (float*)alloc((size_t)G * 512 * 4);
    float*   ps     = (float*)alloc((size_t)G * POOL_NC * 128 * 4);
    float*   pm     = (float*)alloc((size_t)G * POOL_NC * 128 * 4);
    float*   pw     = (float*)alloc((size_t)G * POOL_NC * 128 * 4);
    float*   z1     = (float*)alloc((size_t)G * 256 * 4);
    float*   z2     = (float*)alloc((size_t)G * 128 * 4);
    float*   z3     = (float*)alloc((size_t)G * 64 * 4);
    (void)ws_size;

    const int* e_src = ei;
    const int* e_dst = ei + E;

    // ---- weight prep (single kernel) ----
    transpose_all_kernel<<<352, 256, 0, stream>>>(W1, W2, Wg, Wa1, Wt1, Wt2, Wtg, Wta1);

    // ---- CSR build over dst (reused by all 3 GCN layers) ----
    hipMemsetAsync(cnt, 0, (size_t)N * 4, stream);
    count_rank_kernel<<<(E + 255) / 256, 256, 0, stream>>>(e_dst, cnt, rank, E);
    const int nb = (N + 1023) / 1024;
    scan_local<<<nb, 1024, 0, stream>>>(cnt, rowptr, bsum, dinv, N);
    scan_add<<<nb, 1024, 0, stream>>>(rowptr, bsum, N);
    fill_kernel<<<(E + 255) / 256, 256, 0, stream>>>(e_src, e_dst, dinv, rowptr, rank, csr, E);

    const int rowblocks = (N + 63) / 64;   // 782

    // ---- fused input projection ----
    proj_fused<<<rowblocks, 256, 0, stream>>>(
        x, Wt1, Wt2, b1, g1, be1, b2, g2, be2, hbf, N);

    // ---- GCN layers 1,2: agg -> gemm (bf16 in-place residual) ----
    for (int l = 0; l < 2; ++l) {
        agg_kernel<<<(N + 7) / 8, 256, 0, stream>>>(
            (const ushort4*)hbf, csr, rowptr, dinv, (ushort4*)ahb, N);
        gemm_gcn<<<rowblocks, 256, 0, stream>>>(
            ahb, Wtg + (size_t)l * 16384, bg + (size_t)l * 128,
            gg + (size_t)l * 128, bgg + (size_t)l * 128, hbf, N);
    }

    // ---- GCN layer 3 fused with attention weights ----
    agg_kernel<<<(N + 7) / 8, 256, 0, stream>>>(
        (const ushort4*)hbf, csr, rowptr, dinv, (ushort4*)ahb, N);
    gcn_aw_fused<<<rowblocks, 256, 0, stream>>>(
        ahb, Wtg + (size_t)2 * 16384, bg + (size_t)2 * 128,
        gg + (size_t)2 * 128, bgg + (size_t)2 * 128, hbf,
        Wta1, ba1, Wa2, ba2, aw, N);

    // ---- pooling (h = hbf bf16; bounds inlined) ----
    pool_partial<<<G * POOL_NC, 128, 0, stream>>>(hbf, aw, batch, N, ps, pm, pw);
    pool_final<<<G, 128, 0, stream>>>(ps, pm, pw, batch, N, comb);

    // ---- classifier head (fp32, tiny) ----
    rowgemm2<512, 256, true, true><<<G * 4, 256, 0, stream>>>(comb, Wc1, bc1, gc1, bec1, z1);
    rowgemm2<256, 128, true, true><<<G * 2, 256, 0, stream>>>(z1, Wc2, bc2, gc2, bec2, z2);
    rowgemm2<128, 64,  true, true><<<G * 1, 256, 0, stream>>>(z2, Wc3, bc3, gc3, bec3, z3);
    rowgemm_final<<<G, 64, 0, stream>>>(z3, Wc4, bc4, out);
}